// Round 3
// baseline (121.312 us; speedup 1.0000x reference)
//
#include <hip/hip_runtime.h>
#include <math.h>

#define BS    128
#define NE    512
#define F     6
#define NH    4
#define DPH   4
#define NEMBD 16
#define XPAD  8     // x row stride in floats (6 used + 2 pad for float4 loads)

#if __has_builtin(__builtin_amdgcn_exp2f)
#define EXP2(x) __builtin_amdgcn_exp2f(x)
#else
#define EXP2(x) exp2f(x)
#endif

// ---------------------------------------------------------------------------
// Kernel 0: x := x_in = inp * mask  (padded to 8 floats/entity, pads = 0).
// One thread per (b,entity). attn then atomicAdds head contributions into x.
// ---------------------------------------------------------------------------
__global__ __launch_bounds__(256) void init_x(
    const float* __restrict__ inp, const float* __restrict__ mask,
    float* __restrict__ x)
{
    const int e = blockIdx.x * 256 + threadIdx.x;      // 0 .. BS*NE-1
    const float me = mask[e];
    const float2* rp = (const float2*)(inp + (size_t)e * F);
    const float2 r0 = rp[0], r1 = rp[1], r2 = rp[2];
    float4* o = (float4*)(x + (size_t)e * XPAD);
    o[0] = make_float4(r0.x * me, r0.y * me, r1.x * me, r1.y * me);
    o[1] = make_float4(r2.x * me, r2.y * me, 0.f, 0.f);
}

// ---------------------------------------------------------------------------
// Kernel 1: attention. 1024 blocks = (b, h, half), 256 threads.
// Thread t: chunk c=t&7 (64 keys), rows half*256 + 8g + 0..7 (g=t>>3).
// No-max softmax (verified exact last round); masked keys give e=exp2(0)=1,
// corrected by subtracting (512-N). Butterfly over the lane octet combines
// chunks; each lane then projects its row's att through Wpost (head slice)
// and atomicAdds 6 floats into x.
// ---------------------------------------------------------------------------
#define CH    8
#define CKEYS 64
#define CPAD  65    // float4 stride per chunk: 260 words -> +4 banks per chunk

__global__ __launch_bounds__(256) void attn_kernel(
    const float* __restrict__ inp, const float* __restrict__ mask,
    const float* __restrict__ Wq, const float* __restrict__ Wk,
    const float* __restrict__ Wv, const float* __restrict__ Wpost,
    float* __restrict__ x)
{
    const int blk  = blockIdx.x;
    const int b    = blk >> 3;
    const int h    = (blk >> 1) & 3;
    const int half = blk & 1;
    const int t    = threadIdx.x;
    const int c    = t & 7;
    const int g    = t >> 3;

    __shared__ float4 sk[CH * CPAD];
    __shared__ float4 sv[CH * CPAD];
    __shared__ float  sn[4];

    // ---- stage K/V for entities t and t+256; accumulate mask sum ----
    float mw = 0.f;
    #pragma unroll
    for (int s = 0; s < 2; ++s) {
        const int e = t + s * 256;
        const float me = mask[b * NE + e];
        mw += me;
        const float2* rp = (const float2*)(inp + ((size_t)(b * NE + e)) * F);
        const float2 r0 = rp[0], r1 = rp[1], r2 = rp[2];
        const float x0 = r0.x * me, x1 = r0.y * me, x2 = r1.x * me,
                    x3 = r1.y * me, x4 = r2.x * me, x5 = r2.y * me;
        const float* wk = Wk + h * DPH * F;
        const float* wv = Wv + h * DPH * F;
        float kk[DPH], vv[DPH];
        #pragma unroll
        for (int d = 0; d < DPH; ++d) {
            const float* w = wk + d * F;
            kk[d] = x0*w[0] + x1*w[1] + x2*w[2] + x3*w[3] + x4*w[4] + x5*w[5];
            w = wv + d * F;
            vv[d] = x0*w[0] + x1*w[1] + x2*w[2] + x3*w[3] + x4*w[4] + x5*w[5];
        }
        sk[(e >> 6) * CPAD + (e & 63)] = make_float4(kk[0], kk[1], kk[2], kk[3]);
        sv[(e >> 6) * CPAD + (e & 63)] = make_float4(vv[0], vv[1], vv[2], vv[3]);
    }
    #pragma unroll
    for (int off = 32; off >= 1; off >>= 1) mw += __shfl_down(mw, off);
    if ((t & 63) == 0) sn[t >> 6] = mw;

    // ---- q for this thread's 8 rows; fold 1/sqrt(4) and log2(e) ----
    const float QS = 0.5f * 1.44269504088896340736f;
    float q[8][DPH];
    {
        const float* wq = Wq + h * DPH * F;
        #pragma unroll
        for (int r = 0; r < 8; ++r) {
            const int row = half * 256 + 8 * g + r;
            const float mr = mask[b * NE + row];
            const float2* rp = (const float2*)(inp + ((size_t)(b * NE + row)) * F);
            const float2 r0 = rp[0], r1 = rp[1], r2 = rp[2];
            const float x0 = r0.x * mr, x1 = r0.y * mr, x2 = r1.x * mr,
                        x3 = r1.y * mr, x4 = r2.x * mr, x5 = r2.y * mr;
            #pragma unroll
            for (int d = 0; d < DPH; ++d) {
                const float* w = wq + d * F;
                q[r][d] = QS * (x0*w[0] + x1*w[1] + x2*w[2] + x3*w[3] + x4*w[4] + x5*w[5]);
            }
        }
    }

    __syncthreads();

    const float Nb = sn[0] + sn[1] + sn[2] + sn[3];
    const float lcorr = 512.0f - Nb;      // exact: masked keys contribute e=1

    // ---- inner loop: 64 keys of chunk c × 8 rows ----
    const float4* kb = sk + c * CPAD;
    const float4* vb = sv + c * CPAD;
    float l[8];
    float a[8][DPH];
    #pragma unroll
    for (int r = 0; r < 8; ++r) {
        l[r] = 0.f;
        #pragma unroll
        for (int d = 0; d < DPH; ++d) a[r][d] = 0.f;
    }

    #pragma unroll 2
    for (int j = 0; j < CKEYS; ++j) {
        const float4 kv = kb[j];
        const float4 uv = vb[j];
        #pragma unroll
        for (int r = 0; r < 8; ++r) {
            const float s = fmaf(q[r][0], kv.x, fmaf(q[r][1], kv.y,
                             fmaf(q[r][2], kv.z, q[r][3] * kv.w)));
            const float e = EXP2(s);
            l[r] += e;
            a[r][0] = fmaf(e, uv.x, a[r][0]);
            a[r][1] = fmaf(e, uv.y, a[r][1]);
            a[r][2] = fmaf(e, uv.z, a[r][2]);
            a[r][3] = fmaf(e, uv.w, a[r][3]);
        }
    }

    // ---- butterfly over the octet (combine 8 chunks, all 8 rows) ----
    #pragma unroll
    for (int m = 1; m <= 4; m <<= 1) {
        #pragma unroll
        for (int r = 0; r < 8; ++r) {
            l[r] += __shfl_xor(l[r], m);
            #pragma unroll
            for (int d = 0; d < DPH; ++d) a[r][d] += __shfl_xor(a[r][d], m);
        }
    }

    // ---- lane selects its own row slot r == c (no dynamic reg indexing) ----
    float lsel = l[0], p0 = a[0][0], p1 = a[0][1], p2 = a[0][2], p3 = a[0][3];
    #pragma unroll
    for (int r = 1; r < 8; ++r) {
        if (r == c) { lsel = l[r]; p0 = a[r][0]; p1 = a[r][1]; p2 = a[r][2]; p3 = a[r][3]; }
    }

    const int row = half * 256 + 8 * g + c;
    const float mi = mask[b * NE + row];
    const float lr = lsel - lcorr;
    const float rs = mi / lr;            // masked rows: mi=0 -> 0 (lr=Nb>=1)
    p0 *= rs; p1 *= rs; p2 *= rs; p3 *= rs;

    // ---- head's post-proj contribution: 6 atomics into x ----
    float* xr = x + ((size_t)(b * NE + row)) * XPAD;
    #pragma unroll
    for (int f = 0; f < F; ++f) {
        const float* w = Wpost + f * NEMBD + h * DPH;   // block-uniform -> sgpr
        const float cf = fmaf(p0, w[0], fmaf(p1, w[1], fmaf(p2, w[2], p3 * w[3])));
        atomicAdd(xr + f, cf);
    }
}

// ---------------------------------------------------------------------------
// Kernel 2: per-batch normalization + masked mean pool. 128 blocks x 512.
// x already holds x_in + att@Wpost.T.
// ---------------------------------------------------------------------------
__global__ __launch_bounds__(NE) void epi_kernel(
    const float* __restrict__ mask, const float* __restrict__ x,
    float* __restrict__ out)
{
    const int b = blockIdx.x;
    const int i = threadIdx.x;
    const int wave = i >> 6;
    const int lane = i & 63;

    __shared__ float red[64];

    const float mi = mask[b * NE + i];
    const float4* xr = (const float4*)(x + ((size_t)(b * NE + i)) * XPAD);
    const float4 v0 = xr[0], v1 = xr[1];
    const float xv[F] = {v0.x, v0.y, v0.z, v0.w, v1.x, v1.y};

    // ---- phase 1: S = sum(x), N = sum(mask) ----
    float rsum = xv[0] + xv[1] + xv[2] + xv[3] + xv[4] + xv[5];
    float rn = mi;
    #pragma unroll
    for (int off = 32; off >= 1; off >>= 1) {
        rsum += __shfl_down(rsum, off);
        rn   += __shfl_down(rn, off);
    }
    if (lane == 0) { red[wave * 2] = rsum; red[wave * 2 + 1] = rn; }
    __syncthreads();
    float S = 0.f, N = 0.f;
    #pragma unroll
    for (int w = 0; w < 8; ++w) { S += red[w * 2]; N += red[w * 2 + 1]; }

    const float mu     = S / (6.0f * N);
    const float sum_x2 = S + (NE - N) * 6.0f * mu;
    const float m2     = sum_x2 / (NE * 6.0f);
    const float add    = (1.0f - mi) * mu;

    float ss = 0.f;
    #pragma unroll
    for (int f = 0; f < F; ++f) { const float d = xv[f] + add - m2; ss = fmaf(d, d, ss); }

    // ---- phase 2: sum of squares ----
    __syncthreads();
    #pragma unroll
    for (int off = 32; off >= 1; off >>= 1) ss += __shfl_down(ss, off);
    if (lane == 0) red[wave] = ss;
    __syncthreads();
    float vs = 0.f;
    #pragma unroll
    for (int w = 0; w < 8; ++w) vs += red[w];

    const float var  = vs / (NE * 6.0f - 1.0f);
    const float stdv = sqrtf(var) * sqrtf((6.0f * NE - 1.0f) / (6.0f * N - 1.0f));
    const float inv  = 1.0f / (stdv + 1e-6f);

    float y[F];
    #pragma unroll
    for (int f = 0; f < F; ++f) y[f] = mi * (xv[f] - mu) * inv;

    // ---- phase 3: 6 masked feature sums ----
    __syncthreads();
    #pragma unroll
    for (int off = 32; off >= 1; off >>= 1) {
        #pragma unroll
        for (int f = 0; f < F; ++f) y[f] += __shfl_down(y[f], off);
    }
    if (lane == 0) {
        #pragma unroll
        for (int f = 0; f < F; ++f) red[wave * F + f] = y[f];
    }
    __syncthreads();
    if (i < F) {
        float tt = 0.f;
        #pragma unroll
        for (int w = 0; w < 8; ++w) tt += red[w * F + i];
        out[b * F + i] = tt / N;
    }
}

// ---------------------------------------------------------------------------
extern "C" void kernel_launch(void* const* d_in, const int* in_sizes, int n_in,
                              void* d_out, int out_size, void* d_ws, size_t ws_size,
                              hipStream_t stream) {
    const float* inp   = (const float*)d_in[0];
    const float* mask  = (const float*)d_in[1];
    const float* Wq    = (const float*)d_in[2];
    const float* Wk    = (const float*)d_in[3];
    const float* Wv    = (const float*)d_in[4];
    const float* Wpost = (const float*)d_in[5];
    float* out = (float*)d_out;
    float* x   = (float*)d_ws;   // BS*NE*XPAD floats = 2 MB

    init_x    <<<BS * NE / 256, 256, 0, stream>>>(inp, mask, x);
    attn_kernel<<<BS * NH * 2, 256, 0, stream>>>(inp, mask, Wq, Wk, Wv, Wpost, x);
    epi_kernel <<<BS, NE, 0, stream>>>(mask, x, out);
}

// Round 4
// 103.786 us; speedup vs baseline: 1.1689x; 1.1689x over previous
//
#include <hip/hip_runtime.h>
#include <math.h>

#define BS    128
#define NE    512
#define F     6
#define NH    4
#define DPH   4
#define NEMBD 16

#if __has_builtin(__builtin_amdgcn_exp2f)
#define EXP2(x) __builtin_amdgcn_exp2f(x)
#else
#define EXP2(x) exp2f(x)
#endif

typedef float v2f __attribute__((ext_vector_type(2)));

// ---------------------------------------------------------------------------
// attention: 1024 blocks = (b, h, half), 256 threads.
// Thread t: key-chunk c=t&7 (64 keys), rows half*256 + 8g + 0..7 (g=t>>3),
// processed as 4 float2-packed row pairs (targets v_pk_fma_f32).
// No-max softmax: masked entities have k=v=0 exactly -> e=exp2(0)=1 and zero
// V contribution; l is corrected by subtracting (512-N). Verified r1-r3.
// Octet butterfly combines the 8 chunks; lane writes its row's float4 to att.
// ---------------------------------------------------------------------------
#define CH    8
#define CKEYS 64
#define CPAD  65    // float4 stride/chunk: (c*65+j) mod 8 distinct per c -> no conflicts

__global__ __launch_bounds__(256) void attn_kernel(
    const float* __restrict__ inp, const float* __restrict__ mask,
    const float* __restrict__ Wq, const float* __restrict__ Wk,
    const float* __restrict__ Wv, float* __restrict__ att_out)
{
    const int blk  = blockIdx.x;
    const int b    = blk >> 3;
    const int h    = (blk >> 1) & 3;
    const int half = blk & 1;
    const int t    = threadIdx.x;
    const int c    = t & 7;
    const int g    = t >> 3;

    __shared__ float4 sk[CH * CPAD];
    __shared__ float4 sv[CH * CPAD];
    __shared__ float  sn[4];

    // ---- stage K/V for entities t and t+256; accumulate mask sum ----
    float mw = 0.f;
    #pragma unroll
    for (int s = 0; s < 2; ++s) {
        const int e = t + s * 256;
        const float me = mask[b * NE + e];
        mw += me;
        const float2* rp = (const float2*)(inp + ((size_t)(b * NE + e)) * F);
        const float2 r0 = rp[0], r1 = rp[1], r2 = rp[2];
        const float x0 = r0.x * me, x1 = r0.y * me, x2 = r1.x * me,
                    x3 = r1.y * me, x4 = r2.x * me, x5 = r2.y * me;
        const float* wk = Wk + h * DPH * F;
        const float* wv = Wv + h * DPH * F;
        float kk[DPH], vv[DPH];
        #pragma unroll
        for (int d = 0; d < DPH; ++d) {
            const float* w = wk + d * F;
            kk[d] = x0*w[0] + x1*w[1] + x2*w[2] + x3*w[3] + x4*w[4] + x5*w[5];
            w = wv + d * F;
            vv[d] = x0*w[0] + x1*w[1] + x2*w[2] + x3*w[3] + x4*w[4] + x5*w[5];
        }
        sk[(e >> 6) * CPAD + (e & 63)] = make_float4(kk[0], kk[1], kk[2], kk[3]);
        sv[(e >> 6) * CPAD + (e & 63)] = make_float4(vv[0], vv[1], vv[2], vv[3]);
    }
    #pragma unroll
    for (int off = 32; off >= 1; off >>= 1) mw += __shfl_down(mw, off);
    if ((t & 63) == 0) sn[t >> 6] = mw;

    // ---- q for 8 rows as 4 packed pairs; fold 1/sqrt(4)*log2(e) ----
    const float QS = 0.5f * 1.44269504088896340736f;
    v2f qv[4][DPH];   // [pair][d] = {q_row2p[d], q_row2p+1[d]}
    {
        const float* wq = Wq + h * DPH * F;
        #pragma unroll
        for (int r = 0; r < 8; ++r) {
            const int row = half * 256 + 8 * g + r;
            const float mr = mask[b * NE + row];
            const float2* rp = (const float2*)(inp + ((size_t)(b * NE + row)) * F);
            const float2 r0 = rp[0], r1 = rp[1], r2 = rp[2];
            const float x0 = r0.x * mr, x1 = r0.y * mr, x2 = r1.x * mr,
                        x3 = r1.y * mr, x4 = r2.x * mr, x5 = r2.y * mr;
            #pragma unroll
            for (int d = 0; d < DPH; ++d) {
                const float* w = wq + d * F;
                const float qd = QS * (x0*w[0] + x1*w[1] + x2*w[2] + x3*w[3] + x4*w[4] + x5*w[5]);
                if (r & 1) qv[r >> 1][d].y = qd; else qv[r >> 1][d].x = qd;
            }
        }
    }

    __syncthreads();

    const float Nb = sn[0] + sn[1] + sn[2] + sn[3];
    const float lcorr = 512.0f - Nb;      // exact: masked keys contribute e=1

    // ---- inner loop: 64 keys of chunk c × 4 row pairs (packed fp32) ----
    const float4* kb = sk + c * CPAD;
    const float4* vb = sv + c * CPAD;
    v2f l2[4], a2[4][DPH];
    #pragma unroll
    for (int p = 0; p < 4; ++p) {
        l2[p] = (v2f)(0.f);
        #pragma unroll
        for (int d = 0; d < DPH; ++d) a2[p][d] = (v2f)(0.f);
    }

    #pragma unroll 4
    for (int j = 0; j < CKEYS; ++j) {
        const float4 kv = kb[j];
        const float4 uv = vb[j];
        const v2f kx = (v2f){kv.x, kv.x}, ky = (v2f){kv.y, kv.y},
                  kz = (v2f){kv.z, kv.z}, kw = (v2f){kv.w, kv.w};
        const v2f ux = (v2f){uv.x, uv.x}, uy = (v2f){uv.y, uv.y},
                  uz = (v2f){uv.z, uv.z}, uw = (v2f){uv.w, uv.w};
        #pragma unroll
        for (int p = 0; p < 4; ++p) {
            v2f s = qv[p][3] * kw;
            s = __builtin_elementwise_fma(qv[p][2], kz, s);
            s = __builtin_elementwise_fma(qv[p][1], ky, s);
            s = __builtin_elementwise_fma(qv[p][0], kx, s);
            v2f e;
            e.x = EXP2(s.x);
            e.y = EXP2(s.y);
            l2[p] += e;
            a2[p][0] = __builtin_elementwise_fma(e, ux, a2[p][0]);
            a2[p][1] = __builtin_elementwise_fma(e, uy, a2[p][1]);
            a2[p][2] = __builtin_elementwise_fma(e, uz, a2[p][2]);
            a2[p][3] = __builtin_elementwise_fma(e, uw, a2[p][3]);
        }
    }

    // ---- butterfly over the octet (combine 8 chunks) ----
    #pragma unroll
    for (int m = 1; m <= 4; m <<= 1) {
        #pragma unroll
        for (int p = 0; p < 4; ++p) {
            l2[p].x += __shfl_xor(l2[p].x, m);
            l2[p].y += __shfl_xor(l2[p].y, m);
            #pragma unroll
            for (int d = 0; d < DPH; ++d) {
                a2[p][d].x += __shfl_xor(a2[p][d].x, m);
                a2[p][d].y += __shfl_xor(a2[p][d].y, m);
            }
        }
    }

    // ---- lane selects its own row r == c (static unroll, no dyn indexing) ----
    float lsel = l2[0].x, p0 = a2[0][0].x, p1 = a2[0][1].x,
          p2 = a2[0][2].x, p3 = a2[0][3].x;
    #pragma unroll
    for (int r = 1; r < 8; ++r) {
        if (r == c) {
            const int pp = r >> 1;
            if (r & 1) {
                lsel = l2[pp].y; p0 = a2[pp][0].y; p1 = a2[pp][1].y;
                p2 = a2[pp][2].y; p3 = a2[pp][3].y;
            } else {
                lsel = l2[pp].x; p0 = a2[pp][0].x; p1 = a2[pp][1].x;
                p2 = a2[pp][2].x; p3 = a2[pp][3].x;
            }
        }
    }

    const int row = half * 256 + 8 * g + c;
    const float mi = mask[b * NE + row];
    const float rs = mi / (lsel - lcorr);   // masked rows: mi=0 -> 0
    float4* o = (float4*)(att_out + ((size_t)(b * NE + row)) * NEMBD + h * DPH);
    *o = make_float4(p0 * rs, p1 * rs, p2 * rs, p3 * rs);
}

// ---------------------------------------------------------------------------
// epilogue: post-proj + residual + mask-corrected norm + masked mean pool.
// 128 blocks x 512 threads (round-2 version, verified correct).
// ---------------------------------------------------------------------------
__global__ __launch_bounds__(NE) void epi_kernel(
    const float* __restrict__ inp, const float* __restrict__ mask,
    const float* __restrict__ Wpost, const float* __restrict__ att,
    float* __restrict__ out)
{
    const int b = blockIdx.x;
    const int i = threadIdx.x;
    const int wave = i >> 6;
    const int lane = i & 63;

    __shared__ float swp[F * NEMBD];
    __shared__ float red[64];

    if (i < F * NEMBD) swp[i] = Wpost[i];
    __syncthreads();

    const float mi = mask[b * NE + i];
    const float* row = inp + ((size_t)(b * NE + i)) * F;
    const float* ar  = att + ((size_t)(b * NE + i)) * NEMBD;

    float a[NEMBD];
    #pragma unroll
    for (int t = 0; t < NEMBD; t += 4) {
        const float4 v = *(const float4*)(ar + t);
        a[t] = v.x; a[t+1] = v.y; a[t+2] = v.z; a[t+3] = v.w;
    }

    float x[F];
    #pragma unroll
    for (int f = 0; f < F; ++f) {
        float acc = row[f] * mi;
        #pragma unroll
        for (int t = 0; t < NEMBD; ++t) acc = fmaf(a[t], swp[f * NEMBD + t], acc);
        x[f] = acc;
    }

    // ---- phase 1: S = sum(x), N = sum(mask) ----
    float rsum = x[0] + x[1] + x[2] + x[3] + x[4] + x[5];
    float rn = mi;
    #pragma unroll
    for (int off = 32; off >= 1; off >>= 1) {
        rsum += __shfl_down(rsum, off);
        rn   += __shfl_down(rn, off);
    }
    if (lane == 0) { red[wave * 2] = rsum; red[wave * 2 + 1] = rn; }
    __syncthreads();
    float S = 0.f, N = 0.f;
    #pragma unroll
    for (int w = 0; w < 8; ++w) { S += red[w * 2]; N += red[w * 2 + 1]; }

    const float mu     = S / (6.0f * N);
    const float sum_x2 = S + (NE - N) * 6.0f * mu;
    const float m2     = sum_x2 / (NE * 6.0f);
    const float add    = (1.0f - mi) * mu;

    float ss = 0.f;
    #pragma unroll
    for (int f = 0; f < F; ++f) { const float d = x[f] + add - m2; ss = fmaf(d, d, ss); }

    // ---- phase 2: sum of squares ----
    __syncthreads();
    #pragma unroll
    for (int off = 32; off >= 1; off >>= 1) ss += __shfl_down(ss, off);
    if (lane == 0) red[wave] = ss;
    __syncthreads();
    float vs = 0.f;
    #pragma unroll
    for (int w = 0; w < 8; ++w) vs += red[w];

    const float var  = vs / (NE * 6.0f - 1.0f);
    const float stdv = sqrtf(var) * sqrtf((6.0f * NE - 1.0f) / (6.0f * N - 1.0f));
    const float inv  = 1.0f / (stdv + 1e-6f);

    float y[F];
    #pragma unroll
    for (int f = 0; f < F; ++f) y[f] = mi * (x[f] - mu) * inv;

    // ---- phase 3: 6 masked feature sums ----
    __syncthreads();
    #pragma unroll
    for (int off = 32; off >= 1; off >>= 1) {
        #pragma unroll
        for (int f = 0; f < F; ++f) y[f] += __shfl_down(y[f], off);
    }
    if (lane == 0) {
        #pragma unroll
        for (int f = 0; f < F; ++f) red[wave * F + f] = y[f];
    }
    __syncthreads();
    if (i < F) {
        float tt = 0.f;
        #pragma unroll
        for (int w = 0; w < 8; ++w) tt += red[w * F + i];
        out[b * F + i] = tt / N;
    }
}

// ---------------------------------------------------------------------------
extern "C" void kernel_launch(void* const* d_in, const int* in_sizes, int n_in,
                              void* d_out, int out_size, void* d_ws, size_t ws_size,
                              hipStream_t stream) {
    const float* inp   = (const float*)d_in[0];
    const float* mask  = (const float*)d_in[1];
    const float* Wq    = (const float*)d_in[2];
    const float* Wk    = (const float*)d_in[3];
    const float* Wv    = (const float*)d_in[4];
    const float* Wpost = (const float*)d_in[5];
    float* out = (float*)d_out;
    float* att = (float*)d_ws;   // BS*NE*NEMBD floats = 4 MB

    attn_kernel<<<BS * NH * 2, 256, 0, stream>>>(inp, mask, Wq, Wk, Wv, att);
    epi_kernel <<<BS, NE, 0, stream>>>(inp, mask, Wpost, att, out);
}